// Round 17
// baseline (4756.734 us; speedup 1.0000x reference)
//
#include <hip/hip_runtime.h>
#include <hip/hip_bf16.h>
#include <hip/hip_fp16.h>
#include <cstddef>

// GRU (Keras reset_after=True), persistent kernel + fused MFMA logits v5.
//   gru WG (blockIdx<256): TWO waves. wave0 = compute (R12 protocol: LLC
//   sc0sc1 comm, packed dwordx2 publish via LDS transpose, 24-deep ladder,
//   wz/wr AGPR, wh LDS). wave1 = SENTINEL: continuously gathers the 64
//   producer flags, substitutes own WG's flag with LDS progress word sigo
//   (set by wave0 AFTER its drain), publishes running min to LDS sigr.
//   wave0's per-step wait = ~100cy LDS spin instead of 1-1.5 LLC RT poll,
//   and detection overlaps wave0's publish+drain. Soundness: producers
//   drain data before flag; wave0 loads issue after wave1 saw flags at LLC
//   -> fresh. wave1 exits on sigo==TN (set after wave0's last step).
//   logits role (blockIdx>=256): R15 MFMA workers, unchanged.

#define VOCABN 128
#define HIDN   1024
#define BN     64
#define TN     1024
#define C3N    3072
#define NREP   2      // comm replicas
#define FREP   3      // flag replicas (0,1: gru; 2: logits)
#define NGRU   256
#define NLOG   256

typedef _Float16 half8 __attribute__((ext_vector_type(8)));
typedef float    f32x4 __attribute__((ext_vector_type(4)));
typedef unsigned int u32x4 __attribute__((ext_vector_type(4)));
typedef unsigned int u32x2 __attribute__((ext_vector_type(2)));

// ---------------- Mtab (fp16): M[v][c] = sum_e emb[v][e]*w_in[e][c] + b_in[c]
__global__ __launch_bounds__(256, 1) void emb_gemm(
    const float* __restrict__ emb, const float* __restrict__ w_in,
    const float* __restrict__ b_in, _Float16* __restrict__ Mtab)
{
    __shared__ float se[16][256];
    const int tid = threadIdx.x;
    const int c   = blockIdx.x * 256 + tid;   // 12 x
    const int v0  = blockIdx.y * 16;          // 8 y
#pragma unroll
    for (int i = 0; i < 16; ++i) {
        int flat = i * 256 + tid;
        int r = flat >> 8, e = flat & 255;
        se[r][e] = emb[(v0 + r) * 256 + e];
    }
    __syncthreads();
    float acc[16];
#pragma unroll
    for (int r = 0; r < 16; ++r) acc[r] = 0.f;
    for (int e = 0; e < 256; ++e) {
        float w = w_in[(size_t)e * C3N + c];
#pragma unroll
        for (int r = 0; r < 16; ++r) acc[r] = fmaf(se[r][e], w, acc[r]);
    }
    float bc = b_in[c];
#pragma unroll
    for (int r = 0; r < 16; ++r)
        Mtab[(size_t)(v0 + r) * C3N + c] = (_Float16)(acc[r] + bc);
}

// ---------------- woutf: w_out fp16 in MFMA B-frag order --------------------
__global__ __launch_bounds__(64, 1) void wout_prep(
    const float* __restrict__ w_out, _Float16* __restrict__ woutf)
{
    const int blk = blockIdx.x;               // 0..255 = ct*32+kt
    const int l   = threadIdx.x;
    const int col   = ((blk >> 5) * 16) + (l & 15);
    const int kbase = (blk & 31) * 32 + (l >> 4) * 8;
    half8 v;
#pragma unroll
    for (int e = 0; e < 8; ++e)
        v[e] = (_Float16)w_out[(size_t)(kbase + e) * VOCABN + col];
    *(half8*)(woutf + ((size_t)blk * 64 + l) * 8) = v;
}

// ---------------- fused persistent GRU + MFMA logits ------------------------
// comm (halves): [rep 131072][parity 65536][plane 16384]; flags: [rep 4096 u32]
__global__ __launch_bounds__(256, 1) void fused_persist(
    const int* __restrict__ ids, const _Float16* __restrict__ Mtab_g,
    const float* __restrict__ w_rec, const float* __restrict__ b_rec,
    _Float16* __restrict__ comm,        // NREP * 2 * 65536 halves (512 KB)
    unsigned int* __restrict__ flags,   // FREP * 4096 u32 (48 KB)
    _Float16* __restrict__ hs,          // [T][B][H] fp16
    const _Float16* __restrict__ woutf, // 256 KB fp16 B-frags
    const float* __restrict__ b_out, float* __restrict__ out)
{
    __shared__ __align__(16) char smem[46080];
    _Float16* wh   = (_Float16*)smem;             // gru: 32 KB B-frags
    _Float16* mtab = (_Float16*)(smem + 32768);   // gru: 12 KB
    _Float16* sht  = (_Float16*)(smem + 45056);   // gru: 512 B transpose
    volatile int* sigr = (volatile int*)(smem + 45568);  // min remote flag
    volatile int* sigo = (volatile int*)(smem + 45572);  // own progress
    const half8* whp = (const half8*)wh;

    const int tid = threadIdx.x;

    if (blockIdx.x >= NGRU) {
        // ========== logits role: MFMA, no LDS, 16 tiles/worker ============
        const int wk = blockIdx.x - NGRU;         // 0..255
        const int l  = tid & 63;
        const int mw = tid >> 6;                  // wave = col-tile pair
        const int jl = l & 15, hl = l >> 4;
        const int ct0 = mw * 2, ct1 = mw * 2 + 1;
        const float bo0 = b_out[ct0 * 16 + jl];
        const float bo1 = b_out[ct1 * 16 + jl];
        const _Float16* b0base = woutf + ((size_t)ct0 * 32 * 64 + l) * 8;
        const _Float16* b1base = woutf + ((size_t)ct1 * 32 * 64 + l) * 8;

#define LISS(BUF, P) do { _Pragma("unroll")                                   \
    for (int k8 = 0; k8 < 8; ++k8) {                                          \
        int kt_ = 8*(P) + k8;                                                 \
        asm volatile("global_load_dwordx4 %0, %1, off sc0 sc1"                \
            : "=v"(BUF[3*k8+0]) : "v"(abase + kt_*32) : "memory");            \
        asm volatile("global_load_dwordx4 %0, %1, off"                        \
            : "=v"(BUF[3*k8+1]) : "v"(b0base + kt_*512) : "memory");          \
        asm volatile("global_load_dwordx4 %0, %1, off"                        \
            : "=v"(BUF[3*k8+2]) : "v"(b1base + kt_*512) : "memory");          \
    } } while (0)

#define LWAIT(N) do {                                                         \
    asm volatile("s_waitcnt vmcnt(" #N ")" ::: "memory");                     \
    __builtin_amdgcn_sched_barrier(0); } while (0)

#define LPROC(BUF) do { _Pragma("unroll")                                     \
    for (int k8 = 0; k8 < 8; ++k8) {                                          \
        half8 a_  = __builtin_bit_cast(half8, BUF[3*k8+0]);                   \
        half8 b0_ = __builtin_bit_cast(half8, BUF[3*k8+1]);                   \
        half8 b1_ = __builtin_bit_cast(half8, BUF[3*k8+2]);                   \
        acc0 = __builtin_amdgcn_mfma_f32_16x16x32_f16(a_, b0_, acc0, 0, 0, 0);\
        acc1 = __builtin_amdgcn_mfma_f32_16x16x32_f16(a_, b1_, acc1, 0, 0, 0);\
    } } while (0)

        for (int i = 0; i < 16; ++i) {
            const int tile = wk + NLOG * i;       // t increasing with i
            const int m0   = tile * 16;
            const int tn   = tile >> 2;
            const int pl   = tile & 3;
            {
                const unsigned int* pollp =
                    flags + 2 * 4096 + (l * 4 + pl) * 16;
                const unsigned int tv = (unsigned int)(tn + 1);
                while (true) {
                    unsigned int f;
                    asm volatile("global_load_dword %0, %1, off sc0 sc1\n\t"
                                 "s_waitcnt vmcnt(0)"
                                 : "=v"(f) : "v"(pollp) : "memory");
                    if (__all(f >= tv)) break;
                    __builtin_amdgcn_s_sleep(32);
                }
            }
            __builtin_amdgcn_sched_barrier(0);
            const _Float16* abase = hs + (size_t)(m0 + jl) * HIDN + hl * 8;
            u32x4 PA[24], PB[24];
            f32x4 acc0 = {0.f, 0.f, 0.f, 0.f};
            f32x4 acc1 = {0.f, 0.f, 0.f, 0.f};
            LISS(PA, 0); LISS(PB, 1);             // 48 loads in flight
            LWAIT(24); LPROC(PA); LISS(PA, 2);
            LWAIT(24); LPROC(PB); LISS(PB, 3);
            LWAIT(24); LPROC(PA);
            LWAIT(0);  LPROC(PB);
#pragma unroll
            for (int q = 0; q < 4; ++q) {
                int m = m0 + hl * 4 + q;
                size_t ro = ((size_t)(m & 63) * TN + (m >> 6)) * VOCABN;
                out[ro + ct0 * 16 + jl] = acc0[q] + bo0;
                out[ro + ct1 * 16 + jl] = acc1[q] + bo1;
            }
        }
#undef LISS
#undef LWAIT
#undef LPROC
        return;
    }

    // ==================== gru role: 2 waves ============================
    if (tid >= 128) return;
    const int w  = blockIdx.x & 63;      // column slice
    const int mt = blockIdx.x >> 6;      // plane (batch group of 16)

    if (tid >= 64) {
        // ---------------- wave1: sentinel flag gatherer -------------------
        const int l = tid - 64;
        const unsigned int* pollp = flags + (w & 1) * 4096 + (l * 4 + mt) * 16;
        __syncthreads();                 // wait for wave0 LDS init (sig=0)
        int prev = 0;
        while (true) {
            int own = *sigo;
            if (own >= TN) break;
            unsigned int f;
            asm volatile("global_load_dword %0, %1, off sc0 sc1\n\t"
                         "s_waitcnt vmcnt(0)"
                         : "=v"(f) : "v"(pollp) : "memory");
            if (l == w) f = (unsigned int)own;
            unsigned int m = f;
#pragma unroll
            for (int off = 32; off; off >>= 1) {
                unsigned int o = __shfl_xor(m, off);
                m = o < m ? o : m;
            }
            if ((int)m > prev) {
                prev = (int)m;
                if (l == 0) *sigr = prev;
            }
        }
        return;
    }

    // ---------------- wave0: compute ----------------------------------
    __builtin_amdgcn_s_setprio(1);
    const int l  = tid;                  // 0..63
    const int jj = l & 15;
    const int lh = l >> 4;

    // ---- LDS init: W_h in B-frag order (wave0) ---------------------------
    for (int i = 0; i < 256; ++i) {
        int flat = i * 64 + l;                          // 16384 = 32*64*8
        int e  = flat & 7;
        int ll = (flat >> 3) & 63;
        int kt = flat >> 9;
        int k   = kt * 32 + (ll >> 4) * 8 + e;
        int col = 2048 + w * 16 + (ll & 15);
        wh[(kt * 64 + ll) * 8 + e] = (_Float16)w_rec[(size_t)k * C3N + col];
    }
    for (int i = 0; i < 96; ++i) {
        int flat = i * 64 + l;                          // 6144 = 128*48
        int v = flat / 48, c = flat % 48;
        int col = (c >> 4) * 1024 + w * 16 + (c & 15);
        mtab[v * 48 + c] = Mtab_g[(size_t)v * C3N + col];
    }
    // ---- register(AGPR)-resident weights: z and r gates ------------------
    half8 wz[32], wr[32];
#pragma unroll
    for (int kt = 0; kt < 32; ++kt) {
#pragma unroll
        for (int e = 0; e < 8; ++e) {
            int k = kt * 32 + lh * 8 + e;
            wz[kt][e] = (_Float16)w_rec[(size_t)k * C3N + w * 16 + jj];
            wr[kt][e] = (_Float16)w_rec[(size_t)k * C3N + 1024 + w * 16 + jj];
        }
    }
    const float bz = b_rec[w * 16 + jj];
    const float br = b_rec[1024 + w * 16 + jj];
    const float bh = b_rec[2048 + w * 16 + jj];
    if (l == 0) { *sigr = 0; *sigo = 0; }
    __syncthreads();                     // sig + LDS visible to wave1

    const int bbase = mt * 16 + lh * 4;
    float hprev[4] = {0.f, 0.f, 0.f, 0.f};

    const int ktp = w >> 1;
    _Float16* cw_base = comm + (size_t)mt * 16384 + ktp * 512
                      + (w & 1) * 256 + l * 4;
    const _Float16* cr_base = comm + (size_t)(w & 1) * 131072
                            + (size_t)mt * 16384 + (size_t)l * 8;
    unsigned int* myflag = flags + (w * 4 + mt) * 16;

    const int Bq  = (l >> 1) & 15;                  // batch%16 served
    const int jq  = 8 * (l >> 5) + (l & 1) * 4;     // 4 consecutive jj
    _Float16* hs_base = hs + (size_t)(mt * 16 + Bq) * HIDN + w * 16 + jq;

    int idsv[4];
#pragma unroll
    for (int q = 0; q < 4; ++q) idsv[q] = ids[(size_t)(bbase + q) * TN];

#define ISSUE(BUF, G) do { _Pragma("unroll")                                  \
    for (int i_ = 0; i_ < 8; ++i_)                                            \
        asm volatile("global_load_dwordx4 %0, %1, off sc0 sc1"                \
            : "=v"(BUF[i_]) : "v"(crd + (8*(G)+i_) * 512) : "memory");        \
    } while (0)

#define WAITN(N) do {                                                         \
    asm volatile("s_waitcnt vmcnt(" #N ")" ::: "memory");                     \
    __builtin_amdgcn_sched_barrier(0); } while (0)

#define PROCG(BUF, G) do { _Pragma("unroll")                                  \
    for (int i_ = 0; i_ < 8; ++i_) {                                          \
        half8 a_ = __builtin_bit_cast(half8, BUF[i_]);                        \
        int kt_ = 8*(G) + i_;                                                 \
        acc0 = __builtin_amdgcn_mfma_f32_16x16x32_f16(a_, wz[kt_], acc0, 0, 0, 0); \
        acc1 = __builtin_amdgcn_mfma_f32_16x16x32_f16(a_, wr[kt_], acc1, 0, 0, 0); \
        acc2 = __builtin_amdgcn_mfma_f32_16x16x32_f16(a_, whp[kt_ * 64 + l], acc2, 0, 0, 0); \
    } } while (0)

    for (int t = 0; t < TN; ++t) {
        // ---- wait: sentinel says all producers published h_t -------------
        while (*sigr < t) { }
        __builtin_amdgcn_sched_barrier(0);

        const _Float16* crd = cr_base + (size_t)(t & 1) * 65536;
        u32x4 bA[8], bB[8], bC[8];
        f32x4 acc0 = {0.f, 0.f, 0.f, 0.f};
        f32x4 acc1 = {0.f, 0.f, 0.f, 0.f};
        f32x4 acc2 = {0.f, 0.f, 0.f, 0.f};

        ISSUE(bA, 0); ISSUE(bB, 1); ISSUE(bC, 2);       // 24 loads in flight
        WAITN(16); PROCG(bA, 0); ISSUE(bA, 3);          // chunks 24-31 -> A
        WAITN(16); PROCG(bB, 1);
        WAITN(8);  PROCG(bC, 2);
        WAITN(0);  PROCG(bA, 3);

        // ---- gates (C layout: col=lane&15, row=(lane>>4)*4+q) ------------
        float hnv[4];
#pragma unroll
        for (int q = 0; q < 4; ++q) {
            float az = acc0[q], ar = acc1[q], ah = acc2[q];
            int id = idsv[q];
            float xz = (float)mtab[id * 48 + jj];
            float xr = (float)mtab[id * 48 + 16 + jj];
            float xh = (float)mtab[id * 48 + 32 + jj];
            float z  = 1.f / (1.f + __expf(-(xz + az + bz)));
            float r  = 1.f / (1.f + __expf(-(xr + ar + br)));
            float hh = tanhf(xh + r * (ah + bh));
            float hn = z * hprev[q] + (1.f - z) * hh;
            hprev[q] = hn;
            hnv[q] = hn;
        }
        // ---- LDS transpose -> packed 8B stores: hs + comm replicas -------
#pragma unroll
        for (int q = 0; q < 4; ++q)
            sht[(lh * 4 + q) * 16 + jj] = (_Float16)hnv[q];
        asm volatile("s_waitcnt lgkmcnt(0)" ::: "memory");
        __builtin_amdgcn_sched_barrier(0);
        {
            u32x2 pk = *(const u32x2*)&sht[Bq * 16 + jq];
            _Float16* hp = hs_base + (size_t)t * BN * HIDN;
            asm volatile("global_store_dwordx2 %0, %1, off sc0 sc1"
                         :: "v"(hp), "v"(pk) : "memory");
            _Float16* cwp = cw_base + (size_t)((t + 1) & 1) * 65536;
#pragma unroll
            for (int rr = 0; rr < NREP; ++rr)
                asm volatile("global_store_dwordx2 %0, %1, off sc0 sc1"
                             :: "v"(cwp + rr * 131072), "v"(pk) : "memory");
        }
        // ids prefetch flies during the drain; drain hs+publish, then flag
        if (t + 1 < TN) {
#pragma unroll
            for (int q = 0; q < 4; ++q)
                idsv[q] = ids[(size_t)(bbase + q) * TN + t + 1];
            WAITN(4);                   // 3 stores acked (4 ids loads remain)
        } else {
            WAITN(0);
        }
        if (l == 0) *sigo = t + 1;      // own progress for the sentinel
        if (l == 0) {
            unsigned int fv = (unsigned int)(t + 1);
#pragma unroll
            for (int rr = 0; rr < FREP; ++rr)
                asm volatile("global_store_dword %0, %1, off sc0 sc1"
                             :: "v"(myflag + rr * 4096), "v"(fv) : "memory");
        }
    }
#undef ISSUE
#undef WAITN
#undef PROCG
}

extern "C" void kernel_launch(void* const* d_in, const int* in_sizes, int n_in,
                              void* d_out, int out_size, void* d_ws, size_t ws_size,
                              hipStream_t stream) {
    const int*   ids   = (const int*)d_in[0];
    const float* emb   = (const float*)d_in[1];
    const float* w_in  = (const float*)d_in[2];
    const float* b_in  = (const float*)d_in[3];
    const float* w_rec = (const float*)d_in[4];
    const float* b_rec = (const float*)d_in[5];
    const float* w_out = (const float*)d_in[6];
    const float* b_out = (const float*)d_in[7];
    float* out = (float*)d_out;

    char* ws = (char*)d_ws;
    _Float16* Mtab = (_Float16*)ws;                        // 768 KB (fp16)
    size_t off = (size_t)VOCABN * C3N * 2;
    _Float16* comm = (_Float16*)(ws + off); off += (size_t)NREP * 131072 * 2;  // 512 KB
    unsigned int* flags = (unsigned int*)(ws + off); off += FREP * 4096 * 4;   // 48 KB
    _Float16* woutf = (_Float16*)(ws + off); off += (size_t)HIDN * VOCABN * 2; // 256 KB
    _Float16* hs = (_Float16*)(ws + off);                  // 128 MB

    emb_gemm<<<dim3(12, 8), 256, 0, stream>>>(emb, w_in, b_in, Mtab);
    wout_prep<<<256, 64, 0, stream>>>(w_out, woutf);
    hipMemsetAsync(comm, 0, (size_t)NREP * 131072 * 2, stream);
    hipMemsetAsync(flags, 0, FREP * 4096 * 4, stream);

    fused_persist<<<NGRU + NLOG, 256, 0, stream>>>(
        ids, Mtab, w_rec, b_rec, comm, flags, hs, woutf, b_out, out);
}

// Round 18
// 3827.975 us; speedup vs baseline: 1.2426x; 1.2426x over previous
//
#include <hip/hip_runtime.h>
#include <hip/hip_bf16.h>
#include <hip/hip_fp16.h>
#include <cstddef>

// GRU (Keras reset_after=True), persistent kernel + fused MFMA logits.
// FINAL STRUCTURE (R15, best measured: 3886 us total, 13.4x over baseline):
//   blockIdx < 256 : gru role (one wave per WG) = (col-slice w, plane mt).
//     - weight-stationary: wz/wr register(AGPR)-resident, wh in LDS
//     - h broadcast via LLC (sc0 sc1 device-scope; the only cross-CU
//       coherence point on CDNA4 -- per-XCD L2s unreachable, R11)
//     - per-(w,mt) flags, 2 comm replicas; packed dwordx2 publish via
//       512B LDS transpose (kills partial-line RMW, R12); hs also packed
//     - publish -> drain vmcnt -> flag  =>  flag>=t+1 guarantees data
//     - 24-deep counted-vmcnt load ladder overlaps LLC RT with MFMA
//   blockIdx >= 256: 256 persistent MFMA logits workers (zero LDS,
//     A-frags straight from hs sc0sc1, B-frags from fp16 woutf; 16
//     tiles/worker, per-tile flag poll) -- hides the logits tail under
//     the latency-bound recurrence (R15).
//   Step time ~3.8us = publish-drain RT + flag+detect ~1.5RT + load RT
//   + ~1us compute: a serial-dependence latency floor (1024 steps), not
//   a counter roofline (HBM 3.7%, MfmaUtil 4.4%). Falsified alternatives:
//   flagless tagged comm (R8/R9), XCD-L2 comm (R11), sentinel wave (R17),
//   setprio/no-sleep (R16 null), 4x replication (R6 ~3%).

#define VOCABN 128
#define HIDN   1024
#define BN     64
#define TN     1024
#define C3N    3072
#define NREP   2      // comm replicas
#define FREP   3      // flag replicas (0,1: gru consumers; 2: logits)
#define NGRU   256
#define NLOG   256

typedef _Float16 half8 __attribute__((ext_vector_type(8)));
typedef float    f32x4 __attribute__((ext_vector_type(4)));
typedef unsigned int u32x4 __attribute__((ext_vector_type(4)));
typedef unsigned int u32x2 __attribute__((ext_vector_type(2)));

// ---------------- Mtab (fp16): M[v][c] = sum_e emb[v][e]*w_in[e][c] + b_in[c]
__global__ __launch_bounds__(256, 1) void emb_gemm(
    const float* __restrict__ emb, const float* __restrict__ w_in,
    const float* __restrict__ b_in, _Float16* __restrict__ Mtab)
{
    __shared__ float se[16][256];
    const int tid = threadIdx.x;
    const int c   = blockIdx.x * 256 + tid;   // 12 x
    const int v0  = blockIdx.y * 16;          // 8 y
#pragma unroll
    for (int i = 0; i < 16; ++i) {
        int flat = i * 256 + tid;
        int r = flat >> 8, e = flat & 255;
        se[r][e] = emb[(v0 + r) * 256 + e];
    }
    __syncthreads();
    float acc[16];
#pragma unroll
    for (int r = 0; r < 16; ++r) acc[r] = 0.f;
    for (int e = 0; e < 256; ++e) {
        float w = w_in[(size_t)e * C3N + c];
#pragma unroll
        for (int r = 0; r < 16; ++r) acc[r] = fmaf(se[r][e], w, acc[r]);
    }
    float bc = b_in[c];
#pragma unroll
    for (int r = 0; r < 16; ++r)
        Mtab[(size_t)(v0 + r) * C3N + c] = (_Float16)(acc[r] + bc);
}

// ---------------- woutf: w_out fp16 in MFMA B-frag order --------------------
__global__ __launch_bounds__(64, 1) void wout_prep(
    const float* __restrict__ w_out, _Float16* __restrict__ woutf)
{
    const int blk = blockIdx.x;               // 0..255 = ct*32+kt
    const int l   = threadIdx.x;
    const int col   = ((blk >> 5) * 16) + (l & 15);
    const int kbase = (blk & 31) * 32 + (l >> 4) * 8;
    half8 v;
#pragma unroll
    for (int e = 0; e < 8; ++e)
        v[e] = (_Float16)w_out[(size_t)(kbase + e) * VOCABN + col];
    *(half8*)(woutf + ((size_t)blk * 64 + l) * 8) = v;
}

// ---------------- fused persistent GRU + MFMA logits ------------------------
// comm (halves): [rep 131072][parity 65536][plane 16384]; flags: [rep 4096 u32]
__global__ __launch_bounds__(256, 1) void fused_persist(
    const int* __restrict__ ids, const _Float16* __restrict__ Mtab_g,
    const float* __restrict__ w_rec, const float* __restrict__ b_rec,
    _Float16* __restrict__ comm,        // NREP * 2 * 65536 halves (512 KB)
    unsigned int* __restrict__ flags,   // FREP * 4096 u32 (48 KB)
    _Float16* __restrict__ hs,          // [T][B][H] fp16
    const _Float16* __restrict__ woutf, // 256 KB fp16 B-frags
    const float* __restrict__ b_out, float* __restrict__ out)
{
    __shared__ __align__(16) char smem[46080];
    _Float16* wh   = (_Float16*)smem;             // gru: 32 KB B-frags
    _Float16* mtab = (_Float16*)(smem + 32768);   // gru: 12 KB
    _Float16* sht  = (_Float16*)(smem + 45056);   // gru: 512 B transpose
    const half8* whp = (const half8*)wh;

    const int tid = threadIdx.x;

    if (blockIdx.x >= NGRU) {
        // ========== logits role: MFMA, no LDS, 16 tiles/worker ============
        const int wk = blockIdx.x - NGRU;         // 0..255
        const int l  = tid & 63;
        const int mw = tid >> 6;                  // wave = col-tile pair
        const int jl = l & 15, hl = l >> 4;
        const int ct0 = mw * 2, ct1 = mw * 2 + 1;
        const float bo0 = b_out[ct0 * 16 + jl];
        const float bo1 = b_out[ct1 * 16 + jl];
        const _Float16* b0base = woutf + ((size_t)ct0 * 32 * 64 + l) * 8;
        const _Float16* b1base = woutf + ((size_t)ct1 * 32 * 64 + l) * 8;

#define LISS(BUF, P) do { _Pragma("unroll")                                   \
    for (int k8 = 0; k8 < 8; ++k8) {                                          \
        int kt_ = 8*(P) + k8;                                                 \
        asm volatile("global_load_dwordx4 %0, %1, off sc0 sc1"                \
            : "=v"(BUF[3*k8+0]) : "v"(abase + kt_*32) : "memory");            \
        asm volatile("global_load_dwordx4 %0, %1, off"                        \
            : "=v"(BUF[3*k8+1]) : "v"(b0base + kt_*512) : "memory");          \
        asm volatile("global_load_dwordx4 %0, %1, off"                        \
            : "=v"(BUF[3*k8+2]) : "v"(b1base + kt_*512) : "memory");          \
    } } while (0)

#define LWAIT(N) do {                                                         \
    asm volatile("s_waitcnt vmcnt(" #N ")" ::: "memory");                     \
    __builtin_amdgcn_sched_barrier(0); } while (0)

#define LPROC(BUF) do { _Pragma("unroll")                                     \
    for (int k8 = 0; k8 < 8; ++k8) {                                          \
        half8 a_  = __builtin_bit_cast(half8, BUF[3*k8+0]);                   \
        half8 b0_ = __builtin_bit_cast(half8, BUF[3*k8+1]);                   \
        half8 b1_ = __builtin_bit_cast(half8, BUF[3*k8+2]);                   \
        acc0 = __builtin_amdgcn_mfma_f32_16x16x32_f16(a_, b0_, acc0, 0, 0, 0);\
        acc1 = __builtin_amdgcn_mfma_f32_16x16x32_f16(a_, b1_, acc1, 0, 0, 0);\
    } } while (0)

        for (int i = 0; i < 16; ++i) {
            const int tile = wk + NLOG * i;       // t increasing with i
            const int m0   = tile * 16;
            const int tn   = tile >> 2;
            const int pl   = tile & 3;
            {
                const unsigned int* pollp =
                    flags + 2 * 4096 + (l * 4 + pl) * 16;
                const unsigned int tv = (unsigned int)(tn + 1);
                while (true) {
                    unsigned int f;
                    asm volatile("global_load_dword %0, %1, off sc0 sc1\n\t"
                                 "s_waitcnt vmcnt(0)"
                                 : "=v"(f) : "v"(pollp) : "memory");
                    if (__all(f >= tv)) break;
                    __builtin_amdgcn_s_sleep(32);
                }
            }
            __builtin_amdgcn_sched_barrier(0);
            const _Float16* abase = hs + (size_t)(m0 + jl) * HIDN + hl * 8;
            u32x4 PA[24], PB[24];
            f32x4 acc0 = {0.f, 0.f, 0.f, 0.f};
            f32x4 acc1 = {0.f, 0.f, 0.f, 0.f};
            LISS(PA, 0); LISS(PB, 1);             // 48 loads in flight
            LWAIT(24); LPROC(PA); LISS(PA, 2);
            LWAIT(24); LPROC(PB); LISS(PB, 3);
            LWAIT(24); LPROC(PA);
            LWAIT(0);  LPROC(PB);
#pragma unroll
            for (int q = 0; q < 4; ++q) {
                int m = m0 + hl * 4 + q;
                size_t ro = ((size_t)(m & 63) * TN + (m >> 6)) * VOCABN;
                out[ro + ct0 * 16 + jl] = acc0[q] + bo0;
                out[ro + ct1 * 16 + jl] = acc1[q] + bo1;
            }
        }
#undef LISS
#undef LWAIT
#undef LPROC
        return;
    }

    // ==================== gru role (one wave) ==========================
    if (tid >= 64) return;
    const int l  = tid;                  // 0..63
    const int w  = blockIdx.x & 63;      // column slice
    const int mt = blockIdx.x >> 6;      // plane (batch group of 16)
    const int jj = l & 15;
    const int lh = l >> 4;

    // ---- LDS init: W_h in B-frag order (single wave) ---------------------
    for (int i = 0; i < 256; ++i) {
        int flat = i * 64 + l;                          // 16384 = 32*64*8
        int e  = flat & 7;
        int ll = (flat >> 3) & 63;
        int kt = flat >> 9;
        int k   = kt * 32 + (ll >> 4) * 8 + e;
        int col = 2048 + w * 16 + (ll & 15);
        wh[(kt * 64 + ll) * 8 + e] = (_Float16)w_rec[(size_t)k * C3N + col];
    }
    for (int i = 0; i < 96; ++i) {
        int flat = i * 64 + l;                          // 6144 = 128*48
        int v = flat / 48, c = flat % 48;
        int col = (c >> 4) * 1024 + w * 16 + (c & 15);
        mtab[v * 48 + c] = Mtab_g[(size_t)v * C3N + col];
    }
    // ---- register(AGPR)-resident weights: z and r gates ------------------
    half8 wz[32], wr[32];
#pragma unroll
    for (int kt = 0; kt < 32; ++kt) {
#pragma unroll
        for (int e = 0; e < 8; ++e) {
            int k = kt * 32 + lh * 8 + e;
            wz[kt][e] = (_Float16)w_rec[(size_t)k * C3N + w * 16 + jj];
            wr[kt][e] = (_Float16)w_rec[(size_t)k * C3N + 1024 + w * 16 + jj];
        }
    }
    const float bz = b_rec[w * 16 + jj];
    const float br = b_rec[1024 + w * 16 + jj];
    const float bh = b_rec[2048 + w * 16 + jj];
    asm volatile("s_waitcnt lgkmcnt(0)" ::: "memory");   // LDS init done (1 wave)
    __builtin_amdgcn_sched_barrier(0);

    const int bbase = mt * 16 + lh * 4;
    float hprev[4] = {0.f, 0.f, 0.f, 0.f};

    // packed-publish base: half-offset = ktp*512 + (w&1)*256 + l*4
    const int ktp = w >> 1;
    _Float16* cw_base = comm + (size_t)mt * 16384 + ktp * 512
                      + (w & 1) * 256 + l * 4;
    const _Float16* cr_base = comm + (size_t)(w & 1) * 131072
                            + (size_t)mt * 16384 + (size_t)l * 8;
    unsigned int* myflag = flags + (w * 4 + mt) * 16;
    const unsigned int* pollp = flags + (w & 1) * 4096 + (l * 4 + mt) * 16;

    // packed hs base for this lane's transpose slot (B, jj0)
    const int Bq  = (l >> 1) & 15;                  // batch%16 served
    const int jq  = 8 * (l >> 5) + (l & 1) * 4;     // 4 consecutive jj
    _Float16* hs_base = hs + (size_t)(mt * 16 + Bq) * HIDN + w * 16 + jq;

    int idsv[4];
#pragma unroll
    for (int q = 0; q < 4; ++q) idsv[q] = ids[(size_t)(bbase + q) * TN];

#define ISSUE(BUF, G) do { _Pragma("unroll")                                  \
    for (int i_ = 0; i_ < 8; ++i_)                                            \
        asm volatile("global_load_dwordx4 %0, %1, off sc0 sc1"                \
            : "=v"(BUF[i_]) : "v"(crd + (8*(G)+i_) * 512) : "memory");        \
    } while (0)

#define WAITN(N) do {                                                         \
    asm volatile("s_waitcnt vmcnt(" #N ")" ::: "memory");                     \
    __builtin_amdgcn_sched_barrier(0); } while (0)

#define PROCG(BUF, G) do { _Pragma("unroll")                                  \
    for (int i_ = 0; i_ < 8; ++i_) {                                          \
        half8 a_ = __builtin_bit_cast(half8, BUF[i_]);                        \
        int kt_ = 8*(G) + i_;                                                 \
        acc0 = __builtin_amdgcn_mfma_f32_16x16x32_f16(a_, wz[kt_], acc0, 0, 0, 0); \
        acc1 = __builtin_amdgcn_mfma_f32_16x16x32_f16(a_, wr[kt_], acc1, 0, 0, 0); \
        acc2 = __builtin_amdgcn_mfma_f32_16x16x32_f16(a_, whp[kt_ * 64 + l], acc2, 0, 0, 0); \
    } } while (0)

    for (int t = 0; t < TN; ++t) {
        // ---- poll: 64 producer waves of my plane published h_t -----------
        {
            const unsigned int tv = (unsigned int)t;
            while (true) {
                unsigned int f;
                asm volatile("global_load_dword %0, %1, off sc0 sc1\n\t"
                             "s_waitcnt vmcnt(0)"
                             : "=v"(f) : "v"(pollp) : "memory");
                if (__all(f >= tv)) break;
                __builtin_amdgcn_s_sleep(1);
            }
        }
        __builtin_amdgcn_sched_barrier(0);

        const _Float16* crd = cr_base + (size_t)(t & 1) * 65536;
        u32x4 bA[8], bB[8], bC[8];
        f32x4 acc0 = {0.f, 0.f, 0.f, 0.f};
        f32x4 acc1 = {0.f, 0.f, 0.f, 0.f};
        f32x4 acc2 = {0.f, 0.f, 0.f, 0.f};

        ISSUE(bA, 0); ISSUE(bB, 1); ISSUE(bC, 2);       // 24 loads in flight
        WAITN(16); PROCG(bA, 0); ISSUE(bA, 3);          // chunks 24-31 -> A
        WAITN(16); PROCG(bB, 1);
        WAITN(8);  PROCG(bC, 2);
        WAITN(0);  PROCG(bA, 3);

        // ---- gates (C layout: col=lane&15, row=(lane>>4)*4+q) ------------
        float hnv[4];
#pragma unroll
        for (int q = 0; q < 4; ++q) {
            float az = acc0[q], ar = acc1[q], ah = acc2[q];
            int id = idsv[q];
            float xz = (float)mtab[id * 48 + jj];
            float xr = (float)mtab[id * 48 + 16 + jj];
            float xh = (float)mtab[id * 48 + 32 + jj];
            float z  = 1.f / (1.f + __expf(-(xz + az + bz)));
            float r  = 1.f / (1.f + __expf(-(xr + ar + br)));
            float hh = tanhf(xh + r * (ah + bh));
            float hn = z * hprev[q] + (1.f - z) * hh;
            hprev[q] = hn;
            hnv[q] = hn;
        }
        // ---- LDS transpose -> packed 8B stores: hs + comm replicas -------
#pragma unroll
        for (int q = 0; q < 4; ++q)
            sht[(lh * 4 + q) * 16 + jj] = (_Float16)hnv[q];
        asm volatile("s_waitcnt lgkmcnt(0)" ::: "memory");
        __builtin_amdgcn_sched_barrier(0);
        {
            u32x2 pk = *(const u32x2*)&sht[Bq * 16 + jq];
            _Float16* hp = hs_base + (size_t)t * BN * HIDN;
            asm volatile("global_store_dwordx2 %0, %1, off sc0 sc1"
                         :: "v"(hp), "v"(pk) : "memory");
            _Float16* cwp = cw_base + (size_t)((t + 1) & 1) * 65536;
#pragma unroll
            for (int rr = 0; rr < NREP; ++rr)
                asm volatile("global_store_dwordx2 %0, %1, off sc0 sc1"
                             :: "v"(cwp + rr * 131072), "v"(pk) : "memory");
        }
        // ids prefetch flies during the drain; drain hs+publish, then flag
        if (t + 1 < TN) {
#pragma unroll
            for (int q = 0; q < 4; ++q)
                idsv[q] = ids[(size_t)(bbase + q) * TN + t + 1];
            WAITN(4);                   // 3 stores acked (4 ids loads remain)
        } else {
            WAITN(0);
        }
        if (l == 0) {
            unsigned int fv = (unsigned int)(t + 1);
#pragma unroll
            for (int rr = 0; rr < FREP; ++rr)
                asm volatile("global_store_dword %0, %1, off sc0 sc1"
                             :: "v"(myflag + rr * 4096), "v"(fv) : "memory");
        }
    }
#undef ISSUE
#undef WAITN
#undef PROCG
}

extern "C" void kernel_launch(void* const* d_in, const int* in_sizes, int n_in,
                              void* d_out, int out_size, void* d_ws, size_t ws_size,
                              hipStream_t stream) {
    const int*   ids   = (const int*)d_in[0];
    const float* emb   = (const float*)d_in[1];
    const float* w_in  = (const float*)d_in[2];
    const float* b_in  = (const float*)d_in[3];
    const float* w_rec = (const float*)d_in[4];
    const float* b_rec = (const float*)d_in[5];
    const float* w_out = (const float*)d_in[6];
    const float* b_out = (const float*)d_in[7];
    float* out = (float*)d_out;

    char* ws = (char*)d_ws;
    _Float16* Mtab = (_Float16*)ws;                        // 768 KB (fp16)
    size_t off = (size_t)VOCABN * C3N * 2;
    _Float16* comm = (_Float16*)(ws + off); off += (size_t)NREP * 131072 * 2;  // 512 KB
    unsigned int* flags = (unsigned int*)(ws + off); off += FREP * 4096 * 4;   // 48 KB
    _Float16* woutf = (_Float16*)(ws + off); off += (size_t)HIDN * VOCABN * 2; // 256 KB
    _Float16* hs = (_Float16*)(ws + off);                  // 128 MB

    emb_gemm<<<dim3(12, 8), 256, 0, stream>>>(emb, w_in, b_in, Mtab);
    wout_prep<<<256, 64, 0, stream>>>(w_out, woutf);
    hipMemsetAsync(comm, 0, (size_t)NREP * 131072 * 2, stream);
    hipMemsetAsync(flags, 0, FREP * 4096 * 4, stream);

    fused_persist<<<NGRU + NLOG, 256, 0, stream>>>(
        ids, Mtab, w_rec, b_rec, comm, flags, hs, woutf, b_out, out);
}